// Round 13
// baseline (637.436 us; speedup 1.0000x reference)
//
#include <hip/hip_runtime.h>
#include <hip/hip_bf16.h>
#include <math.h>

#define N_NODES 100000
#define N_EDGES 1600000
#define N_USER  90000
#define NB1     352   // ceil(N_USER/256)
#define NBUCK   256
#define BSZ     352   // targets per bucket; 256*352 = 90112 >= N_USER
#define TILE    2048  // edges per bucket_kernel block

typedef __attribute__((ext_vector_type(8))) short  short8;   // 8 bf16 (4 VGPRs) MFMA A/B frag
typedef __attribute__((ext_vector_type(4))) float  floatx4;  // MFMA C/D frag
typedef unsigned int  uint;
typedef unsigned short ushort;

__device__ __forceinline__ ushort f2bf(float x) {            // RNE fp32 -> bf16
  uint u = __float_as_uint(x);
  u += 0x7fffu + ((u >> 16) & 1u);
  return (ushort)(u >> 16);
}
__device__ __forceinline__ float bf2f(ushort v) { return __uint_as_float(((uint)v) << 16); }

__device__ __forceinline__ void split8(const float v[8], short8& hi, short8& lo) {
  #pragma unroll
  for (int j = 0; j < 8; ++j) {
    ushort h = f2bf(v[j]);
    hi[j] = (short)h;
    lo[j] = (short)f2bf(v[j] - bf2f(h));
  }
}
__device__ __forceinline__ void load_split8(const float* p, short8& hi, short8& lo) {
  const float4* q = (const float4*)p;
  float4 a = q[0], b = q[1];
  float v[8] = {a.x, a.y, a.z, a.w, b.x, b.y, b.z, b.w};
  split8(v, hi, lo);
}
__device__ __forceinline__ float fast_tanh(float x) {
  float t = __expf(2.f * x);
  return 1.f - 2.f / (t + 1.f);
}

// ---------------- hp via MFMA -> packed bf16, exact fp32 logits (one layer) ----------------
__global__ __launch_bounds__(256) void hp_mfma(
    const float* __restrict__ h, const float* __restrict__ w,
    const float* __restrict__ a_src, const float* __restrict__ a_trg,
    uint* __restrict__ hpi, float* __restrict__ attn_src, float* __restrict__ attn_trg)
{
  __shared__ float part[4][16][4];          // [wave][row][as0,as1,at0,at1]
  const int tid = threadIdx.x, lane = tid & 63, wv = tid >> 6;
  const int quad = lane >> 4, l15 = lane & 15;
  const int o = wv * 16 + l15;              // wave's 16-col slice of the 64 outputs
  const float vas0 = a_src[o], vas1 = a_src[64 + o];
  const float vat0 = a_trg[o], vat1 = a_trg[64 + o];
  short8 b0h[2], b0l[2], b1h[2], b1l[2];    // B frags: head0/head1 x ksteps
  #pragma unroll
  for (int ks = 0; ks < 2; ++ks) {
    float v0[8], v1[8];
    #pragma unroll
    for (int j = 0; j < 8; ++j) {
      int k = quad * 8 + j + ks * 32;       // f index
      v0[j] = w[k * 64 + o];                // w[0][f][o]
      v1[j] = w[4096 + k * 64 + o];         // w[1][f][o]
    }
    split8(v0, b0h[ks], b0l[ks]);
    split8(v1, b1h[ks], b1l[ks]);
  }
  for (int t = blockIdx.x; t < N_NODES / 16; t += gridDim.x) {
    int m0 = t * 16, arow = m0 + l15;
    short8 ah[2], al[2];
    #pragma unroll
    for (int ks = 0; ks < 2; ++ks)
      load_split8(h + arow * 64 + quad * 8 + ks * 32, ah[ks], al[ks]);
    floatx4 c0 = {0.f, 0.f, 0.f, 0.f}, c1 = {0.f, 0.f, 0.f, 0.f};
    #pragma unroll
    for (int ks = 0; ks < 2; ++ks) {
      c0 = __builtin_amdgcn_mfma_f32_16x16x32_bf16(ah[ks], b0h[ks], c0, 0, 0, 0);
      c0 = __builtin_amdgcn_mfma_f32_16x16x32_bf16(ah[ks], b0l[ks], c0, 0, 0, 0);
      c0 = __builtin_amdgcn_mfma_f32_16x16x32_bf16(al[ks], b0h[ks], c0, 0, 0, 0);
      c1 = __builtin_amdgcn_mfma_f32_16x16x32_bf16(ah[ks], b1h[ks], c1, 0, 0, 0);
      c1 = __builtin_amdgcn_mfma_f32_16x16x32_bf16(ah[ks], b1l[ks], c1, 0, 0, 0);
      c1 = __builtin_amdgcn_mfma_f32_16x16x32_bf16(al[ks], b1h[ks], c1, 0, 0, 0);
    }
    #pragma unroll
    for (int r = 0; r < 4; ++r) {
      int n = m0 + quad * 4 + r;
      hpi[n * 64 + o] = (uint)f2bf(c0[r]) | ((uint)f2bf(c1[r]) << 16);
    }
    #pragma unroll
    for (int r = 0; r < 4; ++r) {
      float pas0 = c0[r] * vas0, pas1 = c1[r] * vas1;
      float pat0 = c0[r] * vat0, pat1 = c1[r] * vat1;
      #pragma unroll
      for (int m = 1; m < 16; m <<= 1) {
        pas0 += __shfl_xor(pas0, m, 64); pas1 += __shfl_xor(pas1, m, 64);
        pat0 += __shfl_xor(pat0, m, 64); pat1 += __shfl_xor(pat1, m, 64);
      }
      if (l15 == 0) {
        part[wv][quad * 4 + r][0] = pas0; part[wv][quad * 4 + r][1] = pas1;
        part[wv][quad * 4 + r][2] = pat0; part[wv][quad * 4 + r][3] = pat1;
      }
    }
    __syncthreads();
    if (tid < 64) {
      int row = tid & 15, which = tid >> 4;
      float v = part[0][row][which] + part[1][row][which]
              + part[2][row][which] + part[3][row][which];
      int n = m0 + row;
      if (which == 0)      attn_src[n * 2]     = v;
      else if (which == 1) attn_src[n * 2 + 1] = v;
      else if (which == 2) attn_trg[n * 2]     = v;
      else                 attn_trg[n * 2 + 1] = v;
    }
    __syncthreads();
  }
}

// ---------------- CSR build: hist + scans (verbatim), then bucketed 2-level scatter ----------------
__global__ __launch_bounds__(256) void hist_kernel(const int* __restrict__ trg, int* __restrict__ count)
{
  int e = blockIdx.x * 256 + threadIdx.x;
  if (e < N_EDGES) {
    int t = trg[e];
    if (t < N_USER) atomicAdd(&count[t], 1);
  }
}

__global__ __launch_bounds__(256) void scan1_kernel(const int* __restrict__ count,
                                                    int* __restrict__ offs, int* __restrict__ aux)
{
  __shared__ int s[256];
  int i = blockIdx.x * 256 + threadIdx.x;
  int v = (i < N_USER) ? count[i] : 0;
  s[threadIdx.x] = v;
  __syncthreads();
  for (int d = 1; d < 256; d <<= 1) {
    int t = (threadIdx.x >= d) ? s[threadIdx.x - d] : 0;
    __syncthreads();
    s[threadIdx.x] += t;
    __syncthreads();
  }
  if (i < N_USER) offs[i] = s[threadIdx.x] - v;
  if (threadIdx.x == 255) aux[blockIdx.x] = s[255];
}

__global__ __launch_bounds__(512) void scan2_kernel(const int* __restrict__ aux, int* __restrict__ auxex)
{
  __shared__ int s[512];
  int v = (threadIdx.x < NB1) ? aux[threadIdx.x] : 0;
  s[threadIdx.x] = v;
  __syncthreads();
  for (int d = 1; d < 512; d <<= 1) {
    int t = (threadIdx.x >= d) ? s[threadIdx.x - d] : 0;
    __syncthreads();
    s[threadIdx.x] += t;
    __syncthreads();
  }
  if (threadIdx.x < NB1) auxex[threadIdx.x] = s[threadIdx.x] - v;
  if (threadIdx.x == 511) auxex[NB1] = s[511];
}

// scan3 also seeds the (64B-padded) bucket cursors: bucket b starts at offs[b*BSZ].
__global__ __launch_bounds__(256) void scan3_kernel(int* __restrict__ offs, int* __restrict__ cursor,
                                                    const int* __restrict__ auxex, int* __restrict__ bcur)
{
  int i = blockIdx.x * 256 + threadIdx.x;
  if (i < N_USER) {
    int o = offs[i] + auxex[blockIdx.x];
    offs[i] = o;
    cursor[i] = o;
    if ((i % BSZ) == 0) bcur[(i / BSZ) * 16] = o;   // 16-int stride = 1 line/bucket
  }
  if (i == 0) offs[N_USER] = auxex[NB1];
}

// Pass B: bin a 2048-edge tile by bucket in LDS, bulk-append contiguous runs per bucket.
__global__ __launch_bounds__(256) void bucket_kernel(
    const int* __restrict__ src, const int* __restrict__ trg,
    int* __restrict__ bcur, uint2* __restrict__ pairbuf)
{
  __shared__ uint2 plds[TILE];
  __shared__ int bcnt[NBUCK], bscan[NBUCK], gbase[NBUCK];
  const int tid = threadIdx.x;
  const int base = blockIdx.x * TILE;
  bcnt[tid] = 0;
  __syncthreads();
  int myb[8], myr[8];
  uint2 myp[8];
  #pragma unroll
  for (int j = 0; j < 8; ++j) {
    int e = base + j * 256 + tid;
    myb[j] = -1;
    if (e < N_EDGES) {
      int t = trg[e];
      if (t < N_USER) {
        int b = t / BSZ;
        myb[j] = b;
        myr[j] = atomicAdd(&bcnt[b], 1);
        myp[j].x = (uint)src[e];
        myp[j].y = (uint)t;
      }
    }
  }
  __syncthreads();
  gbase[tid] = atomicAdd(&bcur[tid * 16], bcnt[tid]);
  bscan[tid] = bcnt[tid];
  __syncthreads();
  for (int d = 1; d < 256; d <<= 1) {
    int v = (tid >= d) ? bscan[tid - d] : 0;
    __syncthreads();
    bscan[tid] += v;
    __syncthreads();
  }
  #pragma unroll
  for (int j = 0; j < 8; ++j)
    if (myb[j] >= 0) plds[bscan[myb[j]] - bcnt[myb[j]] + myr[j]] = myp[j];
  __syncthreads();
  int total = bscan[NBUCK - 1];
  for (int i = tid; i < total; i += 256) {
    uint2 pr = plds[i];
    int b = (int)pr.y / BSZ;
    int idx = gbase[b] + (i - (bscan[b] - bcnt[b]));
    if (idx >= 0 && idx < N_EDGES) pairbuf[idx] = pr;
  }
}

// Pass C: per-bucket scatter + per-edge weight precompute.
// R12 fix: grid 256 -> 1024 (4 chunks per bucket). 1 block/CU was ~12% occupancy;
// cursor atomics remain correct under any interleaving.
__global__ __launch_bounds__(256) void fine_kernel(
    const uint2* __restrict__ pairbuf, const int* __restrict__ offs,
    int* __restrict__ cursor, int* __restrict__ csr_src,
    const float* __restrict__ attn_src, const float* __restrict__ attn_trg,
    float2* __restrict__ wgt)
{
  const int b = blockIdx.x >> 2;
  const int chunk = blockIdx.x & 3;
  int t0 = b * BSZ, t1 = min(t0 + BSZ, N_USER);
  int pbeg = max(0, offs[t0]);
  int pend = min(offs[t1], N_EDGES);
  int len = pend - pbeg;
  int cbeg = pbeg + (len * chunk) / 4;
  int cend = pbeg + (len * (chunk + 1)) / 4;
  const float2* as2 = (const float2*)attn_src;
  const float2* at2 = (const float2*)attn_trg;
  for (int i = cbeg + threadIdx.x; i < cend; i += 256) {
    uint2 pr = pairbuf[i];
    int s = min((int)pr.x, N_NODES - 1);
    int t = min((int)pr.y, N_USER - 1);
    float2 as = as2[s];
    float2 at = at2[t];
    float e0 = as.x + at.x; e0 = (e0 > 0.f) ? e0 : 0.2f * e0;
    float e1 = as.y + at.y; e1 = (e1 > 0.f) ? e1 : 0.2f * e1;
    int p = atomicAdd(&cursor[t], 1);
    p = min(max(p, 0), N_EDGES - 1);
    csr_src[p] = s;
    wgt[p] = make_float2(__expf(e0), __expf(e1));
  }
}

// ---------------- per-target accumulation: precomputed weights, 8x MLP unroll ----------------
__global__ __launch_bounds__(256) void accum_kernel(
    const int* __restrict__ offs, const int* __restrict__ csr_src,
    const float2* __restrict__ wgt,
    const uint* __restrict__ hpi, float* __restrict__ x)
{
  const int lane = threadIdx.x & 63, wv = threadIdx.x >> 6;
  int n = blockIdx.x * 4 + wv;
  if (n >= N_USER) return;
  int beg = max(0, offs[n]);
  int end = min(offs[n + 1], N_EDGES);
  float acc0 = 0.f, acc1 = 0.f, den0 = 0.f, den1 = 0.f;
  int i = beg;
  for (; i + 8 <= end; i += 8) {
    int s[8];
    float2 W[8];
    uint p[8];
    #pragma unroll
    for (int j = 0; j < 8; ++j) s[j] = min(max(csr_src[i + j], 0), N_NODES - 1);
    #pragma unroll
    for (int j = 0; j < 8; ++j) W[j] = wgt[i + j];
    #pragma unroll
    for (int j = 0; j < 8; ++j) p[j] = hpi[s[j] * 64 + lane];
    #pragma unroll
    for (int j = 0; j < 8; ++j) {
      den0 += W[j].x; den1 += W[j].y;
      acc0 += W[j].x * bf2f((ushort)(p[j] & 0xffff));
      acc1 += W[j].y * bf2f((ushort)(p[j] >> 16));
    }
  }
  for (; i < end; ++i) {
    int s = min(max(csr_src[i], 0), N_NODES - 1);
    float2 W = wgt[i];
    uint pv = hpi[s * 64 + lane];
    den0 += W.x; den1 += W.y;
    acc0 += W.x * bf2f((ushort)(pv & 0xffff));
    acc1 += W.y * bf2f((ushort)(pv >> 16));
  }
  x[n * 64 + lane] = 0.5f * (acc0 / (den0 + 1e-16f) + acc1 / (den1 + 1e-16f));
}

// ---------------- final: 3 MFMA GEMMs + fused epilogue (R12-verbatim, passed) ----------------
__global__ __launch_bounds__(256) void final_mfma(
    const float* __restrict__ h, const float* __restrict__ x0, const float* __restrict__ x1,
    const float* __restrict__ aa_w1, const float* __restrict__ aa_w2, const float* __restrict__ aa_m,
    const float* __restrict__ fc_w, const float* __restrict__ fc_b, float* __restrict__ out)
{
  __shared__ float aam_s[64], fcw_s[384], fcb_s[2];
  __shared__ float scw0[4][16], scw1[4][16];
  const int tid = threadIdx.x;
  if (tid < 64)  aam_s[tid] = aa_m[tid];
  for (int i = tid; i < 384; i += 256) fcw_s[i] = fc_w[i];
  if (tid < 2)   fcb_s[tid] = fc_b[tid];
  const int lane = tid & 63, wv = tid >> 6, quad = lane >> 4, l15 = lane & 15;
  const int d = wv * 16 + l15;
  short8 b1h[2], b1l[2], b2h[2], b2l[2];
  #pragma unroll
  for (int ks = 0; ks < 2; ++ks) {
    load_split8(aa_w1 + d * 64 + quad * 8 + ks * 32, b1h[ks], b1l[ks]);
    load_split8(aa_w2 + d * 64 + quad * 8 + ks * 32, b2h[ks], b2l[ks]);
  }
  __syncthreads();
  for (int t = blockIdx.x; t < N_USER / 16; t += gridDim.x) {
    int m0 = t * 16, arow = m0 + l15;
    short8 ahh[2], ahl[2], a0h[2], a0l[2], a1h[2], a1l[2];
    #pragma unroll
    for (int ks = 0; ks < 2; ++ks) {
      load_split8(h  + arow * 64 + quad * 8 + ks * 32, ahh[ks], ahl[ks]);
      load_split8(x0 + arow * 64 + quad * 8 + ks * 32, a0h[ks], a0l[ks]);
      load_split8(x1 + arow * 64 + quad * 8 + ks * 32, a1h[ks], a1l[ks]);
    }
    floatx4 t1a = {0.f,0.f,0.f,0.f}, t20a = {0.f,0.f,0.f,0.f}, t21a = {0.f,0.f,0.f,0.f};
    #pragma unroll
    for (int ks = 0; ks < 2; ++ks) {
      t1a  = __builtin_amdgcn_mfma_f32_16x16x32_bf16(ahh[ks], b1h[ks], t1a, 0, 0, 0);
      t1a  = __builtin_amdgcn_mfma_f32_16x16x32_bf16(ahh[ks], b1l[ks], t1a, 0, 0, 0);
      t1a  = __builtin_amdgcn_mfma_f32_16x16x32_bf16(ahl[ks], b1h[ks], t1a, 0, 0, 0);
      t20a = __builtin_amdgcn_mfma_f32_16x16x32_bf16(a0h[ks], b2h[ks], t20a, 0, 0, 0);
      t20a = __builtin_amdgcn_mfma_f32_16x16x32_bf16(a0h[ks], b2l[ks], t20a, 0, 0, 0);
      t20a = __builtin_amdgcn_mfma_f32_16x16x32_bf16(a0l[ks], b2h[ks], t20a, 0, 0, 0);
      t21a = __builtin_amdgcn_mfma_f32_16x16x32_bf16(a1h[ks], b2h[ks], t21a, 0, 0, 0);
      t21a = __builtin_amdgcn_mfma_f32_16x16x32_bf16(a1h[ks], b2l[ks], t21a, 0, 0, 0);
      t21a = __builtin_amdgcn_mfma_f32_16x16x32_bf16(a1l[ks], b2h[ks], t21a, 0, 0, 0);
    }
    float am = aam_s[d];
    #pragma unroll
    for (int r = 0; r < 4; ++r) {
      float q0 = fast_tanh(t1a[r] + t20a[r]);
      float q1 = fast_tanh(t1a[r] + t21a[r]);
      float p0 = q0 * am, p1 = q1 * am;
      #pragma unroll
      for (int m = 1; m < 16; m <<= 1) { p0 += __shfl_xor(p0, m, 64); p1 += __shfl_xor(p1, m, 64); }
      if (l15 == 0) { scw0[wv][quad * 4 + r] = p0; scw1[wv][quad * 4 + r] = p1; }
    }
    __syncthreads();
    {
      int row = wv * 4 + quad, n = m0 + row;
      float s0 = scw0[0][row] + scw0[1][row] + scw0[2][row] + scw0[3][row];
      float s1 = scw1[0][row] + scw1[1][row] + scw1[2][row] + scw1[3][row];
      float mx = fmaxf(s0, s1);
      float e0 = __expf(s0 - mx), e1 = __expf(s1 - mx);
      float inv = 1.f / (e0 + e1);
      float b0 = e0 * inv, b1 = e1 * inv;
      float4 v0 = *(const float4*)(x0 + n * 64 + l15 * 4);
      float4 v1 = *(const float4*)(x1 + n * 64 + l15 * 4);
      float a0[4] = {v0.x, v0.y, v0.z, v0.w};
      float a1[4] = {v1.x, v1.y, v1.z, v1.w};
      float pc0 = 0.f, pc1 = 0.f;
      #pragma unroll
      for (int c = 0; c < 4; ++c) {
        int o = l15 * 4 + c;
        float fv = b0 * a0[c] + b1 * a1[c];
        pc0 += fcw_s[o] * a0[c] + fcw_s[64 + o] * a1[c] + fcw_s[128 + o] * fv;
        pc1 += fcw_s[192 + o] * a0[c] + fcw_s[256 + o] * a1[c] + fcw_s[320 + o] * fv;
      }
      #pragma unroll
      for (int m = 1; m < 16; m <<= 1) { pc0 += __shfl_xor(pc0, m, 64); pc1 += __shfl_xor(pc1, m, 64); }
      if (l15 == 0) {
        float l0 = pc0 + fcb_s[0], l1 = pc1 + fcb_s[1];
        float lm = fmaxf(l0, l1);
        float lse = lm + logf(__expf(l0 - lm) + __expf(l1 - lm));
        out[n * 2] = l0 - lse;
        out[n * 2 + 1] = l1 - lse;
      }
    }
    __syncthreads();
  }
}

extern "C" void kernel_launch(void* const* d_in, const int* in_sizes, int n_in,
                              void* d_out, int out_size, void* d_ws, size_t ws_size,
                              hipStream_t stream)
{
  const float* h     = (const float*)d_in[0];
  const int*   src0  = (const int*)d_in[1];
  const int*   trg0  = (const int*)d_in[2];
  const int*   src1  = (const int*)d_in[3];
  const int*   trg1  = (const int*)d_in[4];
  const float* w0    = (const float*)d_in[5];
  const float* asrc0 = (const float*)d_in[6];
  const float* atrg0 = (const float*)d_in[7];
  const float* w1    = (const float*)d_in[8];
  const float* asrc1 = (const float*)d_in[9];
  const float* atrg1 = (const float*)d_in[10];
  const float* aa_w1 = (const float*)d_in[11];
  const float* aa_w2 = (const float*)d_in[12];
  const float* aa_m  = (const float*)d_in[13];
  const float* fc_w  = (const float*)d_in[14];
  const float* fc_b  = (const float*)d_in[15];
  float* out = (float*)d_out;

  char* ws = (char*)d_ws;
  size_t off = 0;
  auto alloc = [&](size_t bytes) -> void* {
    void* p = ws + off;
    off = (off + bytes + 255) & ~(size_t)255;
    return p;
  };
  // total ~106 MB (== R2/R7 proven footprint)
  uint*   hpi      = (uint*)alloc((size_t)N_NODES * 64 * 4);     // 25.6 MB, reused per layer
  float*  attn_src = (float*)alloc((size_t)N_NODES * 2 * 4);
  float*  attn_trg = (float*)alloc((size_t)N_NODES * 2 * 4);
  float*  x0       = (float*)alloc((size_t)N_USER * 64 * 4);     // 23 MB
  float*  x1       = (float*)alloc((size_t)N_USER * 64 * 4);
  int*    count    = (int*)alloc((size_t)N_USER * 4);
  int*    offs     = (int*)alloc((size_t)(N_USER + 1) * 4);
  int*    cursor   = (int*)alloc((size_t)N_USER * 4);
  int*    aux      = (int*)alloc((size_t)NB1 * 4);
  int*    auxex    = (int*)alloc((size_t)(NB1 + 1) * 4);
  int*    csr      = (int*)alloc((size_t)N_EDGES * 4);           // 6.4 MB, reused per layer
  uint2*  pairbuf  = (uint2*)alloc((size_t)N_EDGES * 8);         // 12.8 MB, reused per layer
  float2* wgt      = (float2*)alloc((size_t)N_EDGES * 8);        // 12.8 MB, reused per layer
  int*    bcur     = (int*)alloc((size_t)NBUCK * 16 * 4);        // padded bucket cursors

  const int EB = (N_EDGES + 255) / 256;      // 6250
  const int TB = (N_EDGES + TILE - 1) / TILE;// 782
  for (int layer = 0; layer < 2; ++layer) {
    const float* w    = layer ? w1 : w0;
    const float* asrc = layer ? asrc1 : asrc0;
    const float* atrg = layer ? atrg1 : atrg0;
    const int*   src  = layer ? src1 : src0;
    const int*   trg  = layer ? trg1 : trg0;
    float*       x    = layer ? x1 : x0;
    hipLaunchKernelGGL(hp_mfma, dim3(1024), dim3(256), 0, stream,
                       h, w, asrc, atrg, hpi, attn_src, attn_trg);
    hipMemsetAsync(count, 0, (size_t)N_USER * 4, stream);
    hipLaunchKernelGGL(hist_kernel, dim3(EB), dim3(256), 0, stream, trg, count);
    hipLaunchKernelGGL(scan1_kernel, dim3(NB1), dim3(256), 0, stream, count, offs, aux);
    hipLaunchKernelGGL(scan2_kernel, dim3(1), dim3(512), 0, stream, aux, auxex);
    hipLaunchKernelGGL(scan3_kernel, dim3(NB1), dim3(256), 0, stream, offs, cursor, auxex, bcur);
    hipLaunchKernelGGL(bucket_kernel, dim3(TB), dim3(256), 0, stream, src, trg, bcur, pairbuf);
    hipLaunchKernelGGL(fine_kernel, dim3(NBUCK * 4), dim3(256), 0, stream,
                       pairbuf, offs, cursor, csr, attn_src, attn_trg, wgt);
    hipLaunchKernelGGL(accum_kernel, dim3(N_USER / 4), dim3(256), 0, stream,
                       offs, csr, wgt, hpi, x);
  }
  hipLaunchKernelGGL(final_mfma, dim3(1875), dim3(256), 0, stream,
                     h, x0, x1, aa_w1, aa_w2, aa_m, fc_w, fc_b, out);
}

// Round 14
// 510.269 us; speedup vs baseline: 1.2492x; 1.2492x over previous
//
#include <hip/hip_runtime.h>
#include <hip/hip_bf16.h>
#include <math.h>

#define N_NODES 100000
#define N_EDGES 1600000
#define N_USER  90000
#define NBUCK   256
#define BSZ     352   // targets per bucket; 256*352 = 90112 >= N_USER
#define TILE    2048  // edges per bucket/bhist block

typedef __attribute__((ext_vector_type(8))) short  short8;   // 8 bf16 (4 VGPRs) MFMA A/B frag
typedef __attribute__((ext_vector_type(4))) float  floatx4;  // MFMA C/D frag
typedef unsigned int  uint;
typedef unsigned short ushort;

__device__ __forceinline__ ushort f2bf(float x) {            // RNE fp32 -> bf16
  uint u = __float_as_uint(x);
  u += 0x7fffu + ((u >> 16) & 1u);
  return (ushort)(u >> 16);
}
__device__ __forceinline__ float bf2f(ushort v) { return __uint_as_float(((uint)v) << 16); }

__device__ __forceinline__ void split8(const float v[8], short8& hi, short8& lo) {
  #pragma unroll
  for (int j = 0; j < 8; ++j) {
    ushort h = f2bf(v[j]);
    hi[j] = (short)h;
    lo[j] = (short)f2bf(v[j] - bf2f(h));
  }
}
__device__ __forceinline__ void load_split8(const float* p, short8& hi, short8& lo) {
  const float4* q = (const float4*)p;
  float4 a = q[0], b = q[1];
  float v[8] = {a.x, a.y, a.z, a.w, b.x, b.y, b.z, b.w};
  split8(v, hi, lo);
}
__device__ __forceinline__ float fast_tanh(float x) {
  float t = __expf(2.f * x);
  return 1.f - 2.f / (t + 1.f);
}

// ---------------- hp via MFMA -> packed bf16, exact fp32 logits (one layer) ----------------
__global__ __launch_bounds__(256) void hp_mfma(
    const float* __restrict__ h, const float* __restrict__ w,
    const float* __restrict__ a_src, const float* __restrict__ a_trg,
    uint* __restrict__ hpi, float* __restrict__ attn_src, float* __restrict__ attn_trg)
{
  __shared__ float part[4][16][4];          // [wave][row][as0,as1,at0,at1]
  const int tid = threadIdx.x, lane = tid & 63, wv = tid >> 6;
  const int quad = lane >> 4, l15 = lane & 15;
  const int o = wv * 16 + l15;              // wave's 16-col slice of the 64 outputs
  const float vas0 = a_src[o], vas1 = a_src[64 + o];
  const float vat0 = a_trg[o], vat1 = a_trg[64 + o];
  short8 b0h[2], b0l[2], b1h[2], b1l[2];    // B frags: head0/head1 x ksteps
  #pragma unroll
  for (int ks = 0; ks < 2; ++ks) {
    float v0[8], v1[8];
    #pragma unroll
    for (int j = 0; j < 8; ++j) {
      int k = quad * 8 + j + ks * 32;       // f index
      v0[j] = w[k * 64 + o];                // w[0][f][o]
      v1[j] = w[4096 + k * 64 + o];         // w[1][f][o]
    }
    split8(v0, b0h[ks], b0l[ks]);
    split8(v1, b1h[ks], b1l[ks]);
  }
  for (int t = blockIdx.x; t < N_NODES / 16; t += gridDim.x) {
    int m0 = t * 16, arow = m0 + l15;
    short8 ah[2], al[2];
    #pragma unroll
    for (int ks = 0; ks < 2; ++ks)
      load_split8(h + arow * 64 + quad * 8 + ks * 32, ah[ks], al[ks]);
    floatx4 c0 = {0.f, 0.f, 0.f, 0.f}, c1 = {0.f, 0.f, 0.f, 0.f};
    #pragma unroll
    for (int ks = 0; ks < 2; ++ks) {
      c0 = __builtin_amdgcn_mfma_f32_16x16x32_bf16(ah[ks], b0h[ks], c0, 0, 0, 0);
      c0 = __builtin_amdgcn_mfma_f32_16x16x32_bf16(ah[ks], b0l[ks], c0, 0, 0, 0);
      c0 = __builtin_amdgcn_mfma_f32_16x16x32_bf16(al[ks], b0h[ks], c0, 0, 0, 0);
      c1 = __builtin_amdgcn_mfma_f32_16x16x32_bf16(ah[ks], b1h[ks], c1, 0, 0, 0);
      c1 = __builtin_amdgcn_mfma_f32_16x16x32_bf16(ah[ks], b1l[ks], c1, 0, 0, 0);
      c1 = __builtin_amdgcn_mfma_f32_16x16x32_bf16(al[ks], b1h[ks], c1, 0, 0, 0);
    }
    #pragma unroll
    for (int r = 0; r < 4; ++r) {
      int n = m0 + quad * 4 + r;
      hpi[n * 64 + o] = (uint)f2bf(c0[r]) | ((uint)f2bf(c1[r]) << 16);
    }
    #pragma unroll
    for (int r = 0; r < 4; ++r) {
      float pas0 = c0[r] * vas0, pas1 = c1[r] * vas1;
      float pat0 = c0[r] * vat0, pat1 = c1[r] * vat1;
      #pragma unroll
      for (int m = 1; m < 16; m <<= 1) {
        pas0 += __shfl_xor(pas0, m, 64); pas1 += __shfl_xor(pas1, m, 64);
        pat0 += __shfl_xor(pat0, m, 64); pat1 += __shfl_xor(pat1, m, 64);
      }
      if (l15 == 0) {
        part[wv][quad * 4 + r][0] = pas0; part[wv][quad * 4 + r][1] = pas1;
        part[wv][quad * 4 + r][2] = pat0; part[wv][quad * 4 + r][3] = pat1;
      }
    }
    __syncthreads();
    if (tid < 64) {
      int row = tid & 15, which = tid >> 4;
      float v = part[0][row][which] + part[1][row][which]
              + part[2][row][which] + part[3][row][which];
      int n = m0 + row;
      if (which == 0)      attn_src[n * 2]     = v;
      else if (which == 1) attn_src[n * 2 + 1] = v;
      else if (which == 2) attn_trg[n * 2]     = v;
      else                 attn_trg[n * 2 + 1] = v;
    }
    __syncthreads();
  }
}

// ---------------- bucket histogram (replaces per-target hist + 90K scan) ----------------
// LDS-merged: 200K low-contention global atomics on 256 counters instead of hist's
// 1.6M random atomics over 360 KB (cross-XCD RMW pathology).
__global__ __launch_bounds__(256) void bhist_kernel(const int* __restrict__ trg, int* __restrict__ bhist)
{
  __shared__ int hh[NBUCK];
  hh[threadIdx.x] = 0;
  __syncthreads();
  const int base = blockIdx.x * TILE;
  #pragma unroll
  for (int j = 0; j < 8; ++j) {
    int e = base + j * 256 + threadIdx.x;
    if (e < N_EDGES) {
      int t = trg[e];
      if (t < N_USER) atomicAdd(&hh[t / BSZ], 1);
    }
  }
  __syncthreads();
  if (hh[threadIdx.x]) atomicAdd(&bhist[threadIdx.x], hh[threadIdx.x]);
}

// 1-block scan of the 256 bucket sizes -> bstart[257] + seeded (padded) bucket cursors.
__global__ __launch_bounds__(256) void scanb_kernel(const int* __restrict__ bhist,
                                                    int* __restrict__ bstart, int* __restrict__ bcur)
{
  __shared__ int s[256];
  int v = bhist[threadIdx.x];
  s[threadIdx.x] = v;
  __syncthreads();
  for (int d = 1; d < 256; d <<= 1) {
    int t = (threadIdx.x >= d) ? s[threadIdx.x - d] : 0;
    __syncthreads();
    s[threadIdx.x] += t;
    __syncthreads();
  }
  int excl = s[threadIdx.x] - v;
  bstart[threadIdx.x] = excl;
  bcur[threadIdx.x * 16] = excl;
  if (threadIdx.x == 255) bstart[256] = s[255];
}

// Pass B: bin a 2048-edge tile by bucket in LDS, bulk-append contiguous runs per bucket.
__global__ __launch_bounds__(256) void bucket_kernel(
    const int* __restrict__ src, const int* __restrict__ trg,
    int* __restrict__ bcur, uint2* __restrict__ pairbuf)
{
  __shared__ uint2 plds[TILE];
  __shared__ int bcnt[NBUCK], bscan[NBUCK], gbase[NBUCK];
  const int tid = threadIdx.x;
  const int base = blockIdx.x * TILE;
  bcnt[tid] = 0;
  __syncthreads();
  int myb[8], myr[8];
  uint2 myp[8];
  #pragma unroll
  for (int j = 0; j < 8; ++j) {
    int e = base + j * 256 + tid;
    myb[j] = -1;
    if (e < N_EDGES) {
      int t = trg[e];
      if (t < N_USER) {
        int b = t / BSZ;
        myb[j] = b;
        myr[j] = atomicAdd(&bcnt[b], 1);
        myp[j].x = (uint)src[e];
        myp[j].y = (uint)t;
      }
    }
  }
  __syncthreads();
  gbase[tid] = atomicAdd(&bcur[tid * 16], bcnt[tid]);
  bscan[tid] = bcnt[tid];
  __syncthreads();
  for (int d = 1; d < 256; d <<= 1) {
    int v = (tid >= d) ? bscan[tid - d] : 0;
    __syncthreads();
    bscan[tid] += v;
    __syncthreads();
  }
  #pragma unroll
  for (int j = 0; j < 8; ++j)
    if (myb[j] >= 0) plds[bscan[myb[j]] - bcnt[myb[j]] + myr[j]] = myp[j];
  __syncthreads();
  int total = bscan[NBUCK - 1];
  for (int i = tid; i < total; i += 256) {
    uint2 pr = plds[i];
    int b = (int)pr.y / BSZ;
    int idx = gbase[b] + (i - (bscan[b] - bcnt[b]));
    if (idx >= 0 && idx < N_EDGES) pairbuf[idx] = pr;
  }
}

// Pass C: one block per bucket. Builds per-target offs LOCALLY in LDS (count ->
// serial scan -> LDS cursors), then scatters csr/wgt with all cursor atomics in LDS.
// Replaces the global hist/scan1/scan2/scan3 pipeline entirely.
__global__ __launch_bounds__(256) void fine_kernel(
    const uint2* __restrict__ pairbuf, const int* __restrict__ bstart,
    int* __restrict__ offs, int* __restrict__ csr_src,
    const float* __restrict__ attn_src, const float* __restrict__ attn_trg,
    float2* __restrict__ wgt)
{
  __shared__ int cnt[BSZ + 1];
  __shared__ int cur[BSZ];
  const int b = blockIdx.x, tid = threadIdx.x;
  const int t0 = b * BSZ;
  const int nt = min(BSZ, N_USER - t0);     // 240 for bucket 255
  const int pbeg = bstart[b], pend = bstart[b + 1];
  for (int j = tid; j <= BSZ; j += 256) cnt[j] = 0;
  __syncthreads();
  for (int i = pbeg + tid; i < pend; i += 256) {
    int tl = (int)pairbuf[i].y - t0;
    tl = min(max(tl, 0), BSZ - 1);
    atomicAdd(&cnt[tl], 1);
  }
  __syncthreads();
  if (tid == 0) {                           // serial exclusive scan, <=352 elems (~3 us)
    int run = 0;
    for (int j = 0; j < nt; ++j) { int c = cnt[j]; cnt[j] = run; run += c; }
    cnt[nt] = run;
  }
  __syncthreads();
  for (int j = tid; j < nt; j += 256) {
    offs[t0 + j] = pbeg + cnt[j];
    cur[j] = cnt[j];
  }
  if (tid == 0 && t0 + nt == N_USER) offs[N_USER] = pbeg + cnt[nt];
  __syncthreads();
  const float2* as2 = (const float2*)attn_src;
  const float2* at2 = (const float2*)attn_trg;
  for (int i = pbeg + tid; i < pend; i += 256) {
    uint2 pr = pairbuf[i];
    int s = min((int)pr.x, N_NODES - 1);
    int tt = min((int)pr.y, N_USER - 1);
    int tl = min(max(tt - t0, 0), BSZ - 1);
    float2 as = as2[s];
    float2 at = at2[tt];
    float e0 = as.x + at.x; e0 = (e0 > 0.f) ? e0 : 0.2f * e0;
    float e1 = as.y + at.y; e1 = (e1 > 0.f) ? e1 : 0.2f * e1;
    int p = pbeg + atomicAdd(&cur[tl], 1);
    p = min(max(p, 0), N_EDGES - 1);
    csr_src[p] = s;
    wgt[p] = make_float2(__expf(e0), __expf(e1));
  }
}

// ---------------- per-target accumulation: precomputed weights, 4x MLP unroll (R12-verbatim) ----------------
__global__ __launch_bounds__(256) void accum_kernel(
    const int* __restrict__ offs, const int* __restrict__ csr_src,
    const float2* __restrict__ wgt,
    const uint* __restrict__ hpi, float* __restrict__ x)
{
  const int lane = threadIdx.x & 63, wv = threadIdx.x >> 6;
  int n = blockIdx.x * 4 + wv;
  if (n >= N_USER) return;
  int beg = max(0, offs[n]);
  int end = min(offs[n + 1], N_EDGES);
  float acc0 = 0.f, acc1 = 0.f, den0 = 0.f, den1 = 0.f;
  int i = beg;
  for (; i + 4 <= end; i += 4) {
    int s0 = min(max(csr_src[i], 0), N_NODES - 1);
    int s1 = min(max(csr_src[i + 1], 0), N_NODES - 1);
    int s2 = min(max(csr_src[i + 2], 0), N_NODES - 1);
    int s3 = min(max(csr_src[i + 3], 0), N_NODES - 1);
    float2 W0 = wgt[i];
    float2 W1 = wgt[i + 1];
    float2 W2 = wgt[i + 2];
    float2 W3 = wgt[i + 3];
    uint p0 = hpi[s0 * 64 + lane];
    uint p1 = hpi[s1 * 64 + lane];
    uint p2 = hpi[s2 * 64 + lane];
    uint p3 = hpi[s3 * 64 + lane];
    den0 += W0.x + W1.x + W2.x + W3.x;
    den1 += W0.y + W1.y + W2.y + W3.y;
    acc0 += W0.x * bf2f((ushort)(p0 & 0xffff)) + W1.x * bf2f((ushort)(p1 & 0xffff))
          + W2.x * bf2f((ushort)(p2 & 0xffff)) + W3.x * bf2f((ushort)(p3 & 0xffff));
    acc1 += W0.y * bf2f((ushort)(p0 >> 16)) + W1.y * bf2f((ushort)(p1 >> 16))
          + W2.y * bf2f((ushort)(p2 >> 16)) + W3.y * bf2f((ushort)(p3 >> 16));
  }
  for (; i < end; ++i) {
    int s = min(max(csr_src[i], 0), N_NODES - 1);
    float2 W = wgt[i];
    uint pv = hpi[s * 64 + lane];
    den0 += W.x; den1 += W.y;
    acc0 += W.x * bf2f((ushort)(pv & 0xffff));
    acc1 += W.y * bf2f((ushort)(pv >> 16));
  }
  x[n * 64 + lane] = 0.5f * (acc0 / (den0 + 1e-16f) + acc1 / (den1 + 1e-16f));
}

// ---------------- final: 3 MFMA GEMMs + fused epilogue (R12-verbatim, passed) ----------------
__global__ __launch_bounds__(256) void final_mfma(
    const float* __restrict__ h, const float* __restrict__ x0, const float* __restrict__ x1,
    const float* __restrict__ aa_w1, const float* __restrict__ aa_w2, const float* __restrict__ aa_m,
    const float* __restrict__ fc_w, const float* __restrict__ fc_b, float* __restrict__ out)
{
  __shared__ float aam_s[64], fcw_s[384], fcb_s[2];
  __shared__ float scw0[4][16], scw1[4][16];
  const int tid = threadIdx.x;
  if (tid < 64)  aam_s[tid] = aa_m[tid];
  for (int i = tid; i < 384; i += 256) fcw_s[i] = fc_w[i];
  if (tid < 2)   fcb_s[tid] = fc_b[tid];
  const int lane = tid & 63, wv = tid >> 6, quad = lane >> 4, l15 = lane & 15;
  const int d = wv * 16 + l15;
  short8 b1h[2], b1l[2], b2h[2], b2l[2];
  #pragma unroll
  for (int ks = 0; ks < 2; ++ks) {
    load_split8(aa_w1 + d * 64 + quad * 8 + ks * 32, b1h[ks], b1l[ks]);
    load_split8(aa_w2 + d * 64 + quad * 8 + ks * 32, b2h[ks], b2l[ks]);
  }
  __syncthreads();
  for (int t = blockIdx.x; t < N_USER / 16; t += gridDim.x) {
    int m0 = t * 16, arow = m0 + l15;
    short8 ahh[2], ahl[2], a0h[2], a0l[2], a1h[2], a1l[2];
    #pragma unroll
    for (int ks = 0; ks < 2; ++ks) {
      load_split8(h  + arow * 64 + quad * 8 + ks * 32, ahh[ks], ahl[ks]);
      load_split8(x0 + arow * 64 + quad * 8 + ks * 32, a0h[ks], a0l[ks]);
      load_split8(x1 + arow * 64 + quad * 8 + ks * 32, a1h[ks], a1l[ks]);
    }
    floatx4 t1a = {0.f,0.f,0.f,0.f}, t20a = {0.f,0.f,0.f,0.f}, t21a = {0.f,0.f,0.f,0.f};
    #pragma unroll
    for (int ks = 0; ks < 2; ++ks) {
      t1a  = __builtin_amdgcn_mfma_f32_16x16x32_bf16(ahh[ks], b1h[ks], t1a, 0, 0, 0);
      t1a  = __builtin_amdgcn_mfma_f32_16x16x32_bf16(ahh[ks], b1l[ks], t1a, 0, 0, 0);
      t1a  = __builtin_amdgcn_mfma_f32_16x16x32_bf16(ahl[ks], b1h[ks], t1a, 0, 0, 0);
      t20a = __builtin_amdgcn_mfma_f32_16x16x32_bf16(a0h[ks], b2h[ks], t20a, 0, 0, 0);
      t20a = __builtin_amdgcn_mfma_f32_16x16x32_bf16(a0h[ks], b2l[ks], t20a, 0, 0, 0);
      t20a = __builtin_amdgcn_mfma_f32_16x16x32_bf16(a0l[ks], b2h[ks], t20a, 0, 0, 0);
      t21a = __builtin_amdgcn_mfma_f32_16x16x32_bf16(a1h[ks], b2h[ks], t21a, 0, 0, 0);
      t21a = __builtin_amdgcn_mfma_f32_16x16x32_bf16(a1h[ks], b2l[ks], t21a, 0, 0, 0);
      t21a = __builtin_amdgcn_mfma_f32_16x16x32_bf16(a1l[ks], b2h[ks], t21a, 0, 0, 0);
    }
    float am = aam_s[d];
    #pragma unroll
    for (int r = 0; r < 4; ++r) {
      float q0 = fast_tanh(t1a[r] + t20a[r]);
      float q1 = fast_tanh(t1a[r] + t21a[r]);
      float p0 = q0 * am, p1 = q1 * am;
      #pragma unroll
      for (int m = 1; m < 16; m <<= 1) { p0 += __shfl_xor(p0, m, 64); p1 += __shfl_xor(p1, m, 64); }
      if (l15 == 0) { scw0[wv][quad * 4 + r] = p0; scw1[wv][quad * 4 + r] = p1; }
    }
    __syncthreads();
    {
      int row = wv * 4 + quad, n = m0 + row;
      float s0 = scw0[0][row] + scw0[1][row] + scw0[2][row] + scw0[3][row];
      float s1 = scw1[0][row] + scw1[1][row] + scw1[2][row] + scw1[3][row];
      float mx = fmaxf(s0, s1);
      float e0 = __expf(s0 - mx), e1 = __expf(s1 - mx);
      float inv = 1.f / (e0 + e1);
      float b0 = e0 * inv, b1 = e1 * inv;
      float4 v0 = *(const float4*)(x0 + n * 64 + l15 * 4);
      float4 v1 = *(const float4*)(x1 + n * 64 + l15 * 4);
      float a0[4] = {v0.x, v0.y, v0.z, v0.w};
      float a1[4] = {v1.x, v1.y, v1.z, v1.w};
      float pc0 = 0.f, pc1 = 0.f;
      #pragma unroll
      for (int c = 0; c < 4; ++c) {
        int o = l15 * 4 + c;
        float fv = b0 * a0[c] + b1 * a1[c];
        pc0 += fcw_s[o] * a0[c] + fcw_s[64 + o] * a1[c] + fcw_s[128 + o] * fv;
        pc1 += fcw_s[192 + o] * a0[c] + fcw_s[256 + o] * a1[c] + fcw_s[320 + o] * fv;
      }
      #pragma unroll
      for (int m = 1; m < 16; m <<= 1) { pc0 += __shfl_xor(pc0, m, 64); pc1 += __shfl_xor(pc1, m, 64); }
      if (l15 == 0) {
        float l0 = pc0 + fcb_s[0], l1 = pc1 + fcb_s[1];
        float lm = fmaxf(l0, l1);
        float lse = lm + logf(__expf(l0 - lm) + __expf(l1 - lm));
        out[n * 2] = l0 - lse;
        out[n * 2 + 1] = l1 - lse;
      }
    }
    __syncthreads();
  }
}

extern "C" void kernel_launch(void* const* d_in, const int* in_sizes, int n_in,
                              void* d_out, int out_size, void* d_ws, size_t ws_size,
                              hipStream_t stream)
{
  const float* h     = (const float*)d_in[0];
  const int*   src0  = (const int*)d_in[1];
  const int*   trg0  = (const int*)d_in[2];
  const int*   src1  = (const int*)d_in[3];
  const int*   trg1  = (const int*)d_in[4];
  const float* w0    = (const float*)d_in[5];
  const float* asrc0 = (const float*)d_in[6];
  const float* atrg0 = (const float*)d_in[7];
  const float* w1    = (const float*)d_in[8];
  const float* asrc1 = (const float*)d_in[9];
  const float* atrg1 = (const float*)d_in[10];
  const float* aa_w1 = (const float*)d_in[11];
  const float* aa_w2 = (const float*)d_in[12];
  const float* aa_m  = (const float*)d_in[13];
  const float* fc_w  = (const float*)d_in[14];
  const float* fc_b  = (const float*)d_in[15];
  float* out = (float*)d_out;

  char* ws = (char*)d_ws;
  size_t off = 0;
  auto alloc = [&](size_t bytes) -> void* {
    void* p = ws + off;
    off = (off + bytes + 255) & ~(size_t)255;
    return p;
  };
  // total ~105 MB (<= R2/R7 proven footprint)
  uint*   hpi      = (uint*)alloc((size_t)N_NODES * 64 * 4);     // 25.6 MB, reused per layer
  float*  attn_src = (float*)alloc((size_t)N_NODES * 2 * 4);
  float*  attn_trg = (float*)alloc((size_t)N_NODES * 2 * 4);
  float*  x0       = (float*)alloc((size_t)N_USER * 64 * 4);     // 23 MB
  float*  x1       = (float*)alloc((size_t)N_USER * 64 * 4);
  int*    offs     = (int*)alloc((size_t)(N_USER + 1) * 4);
  int*    csr      = (int*)alloc((size_t)N_EDGES * 4);           // 6.4 MB, reused per layer
  uint2*  pairbuf  = (uint2*)alloc((size_t)N_EDGES * 8);         // 12.8 MB, reused per layer
  float2* wgt      = (float2*)alloc((size_t)N_EDGES * 8);        // 12.8 MB, reused per layer
  int*    bhist    = (int*)alloc((size_t)NBUCK * 4);
  int*    bstart   = (int*)alloc((size_t)(NBUCK + 1) * 4);
  int*    bcur     = (int*)alloc((size_t)NBUCK * 16 * 4);        // padded bucket cursors

  const int TB = (N_EDGES + TILE - 1) / TILE;   // 782
  for (int layer = 0; layer < 2; ++layer) {
    const float* w    = layer ? w1 : w0;
    const float* asrc = layer ? asrc1 : asrc0;
    const float* atrg = layer ? atrg1 : atrg0;
    const int*   src  = layer ? src1 : src0;
    const int*   trg  = layer ? trg1 : trg0;
    float*       x    = layer ? x1 : x0;
    hipLaunchKernelGGL(hp_mfma, dim3(1024), dim3(256), 0, stream,
                       h, w, asrc, atrg, hpi, attn_src, attn_trg);
    hipMemsetAsync(bhist, 0, (size_t)NBUCK * 4, stream);
    hipLaunchKernelGGL(bhist_kernel, dim3(TB), dim3(256), 0, stream, trg, bhist);
    hipLaunchKernelGGL(scanb_kernel, dim3(1), dim3(256), 0, stream, bhist, bstart, bcur);
    hipLaunchKernelGGL(bucket_kernel, dim3(TB), dim3(256), 0, stream, src, trg, bcur, pairbuf);
    hipLaunchKernelGGL(fine_kernel, dim3(NBUCK), dim3(256), 0, stream,
                       pairbuf, bstart, offs, csr, attn_src, attn_trg, wgt);
    hipLaunchKernelGGL(accum_kernel, dim3(N_USER / 4), dim3(256), 0, stream,
                       offs, csr, wgt, hpi, x);
  }
  hipLaunchKernelGGL(final_mfma, dim3(1875), dim3(256), 0, stream,
                     h, x0, x1, aa_w1, aa_w2, aa_m, fc_w, fc_b, out);
}